// Round 3
// baseline (454.469 us; speedup 1.0000x reference)
//
#include <hip/hip_runtime.h>

#define BB 8
#define NN 1024
#define CC 64
#define TT 12
#define OO 64

typedef unsigned short u16;
typedef __attribute__((ext_vector_type(8))) short s16x8;
typedef __attribute__((ext_vector_type(4))) float f32x4;

__device__ __forceinline__ u16 f2bu(float f){
  union { float f; unsigned u; } v; v.f = f;
  unsigned r = v.u + 0x7FFFu + ((v.u >> 16) & 1u);
  return (u16)(r >> 16);
}
__device__ __forceinline__ float b2f(u16 h){
  union { unsigned u; float f; } v; v.u = ((unsigned)h) << 16; return v.f;
}
__device__ __forceinline__ float tanh_pos(float x){   // x >= 0
  float e = __expf(2.0f * x);
  return 1.0f - 2.0f * __builtin_amdgcn_rcpf(e + 1.0f);
}
__device__ __forceinline__ float tanh_sgn(float x){
  float t = tanh_pos(fabsf(x));
  return x < 0.0f ? -t : t;
}

#define MFMA16(a,b,c) __builtin_amdgcn_mfma_f32_16x16x32_bf16((a),(b),(c),0,0,0)

// frag load from padded-72 row-major LDS tile (row stride 144B, 16B aligned)
__device__ __forceinline__ s16x8 ld72(const u16* s, int row0, int ko, int lane){
  return *(const s16x8*)(s + (row0 + (lane & 15)) * 72 + ko + ((lane >> 4) << 3));
}

// ---------------- K0: x [B,N,C,T] f32 -> xt [T,B,N,C] bf16 ----------------
__global__ __launch_bounds__(256) void k0_transpose(const float* __restrict__ x,
                                                    u16* __restrict__ xt){
  const int n = blockIdx.x, b = blockIdx.y;
  __shared__ float s[CC*TT];
  const float* src = x + (size_t)(b*NN + n)*CC*TT;
  for (int k = threadIdx.x; k < CC*TT; k += 256) s[k] = src[k];
  __syncthreads();
  for (int k = threadIdx.x; k < CC*TT; k += 256){
    const int t = k >> 6, c = k & 63;
    xt[(((size_t)t*BB + b)*NN + n)*CC + c] = f2bu(s[c*TT + t]);
  }
}

// ---------------- kadj: adj f32 -> bf16 ----------------
__global__ __launch_bounds__(256) void kadj(const float* __restrict__ adj,
                                            u16* __restrict__ adjb){
  const size_t i = ((size_t)blockIdx.x*256 + threadIdx.x)*4;
  const float4 v = *(const float4*)(adj + i);
  u16 o0=f2bu(v.x), o1=f2bu(v.y), o2=f2bu(v.z), o3=f2bu(v.w);
  adjb[i]=o0; adjb[i+1]=o1; adjb[i+2]=o2; adjb[i+3]=o3;
}

__global__ __launch_bounds__(256) void kinit(float* __restrict__ rs){
  const size_t i = (size_t)blockIdx.x*256 + threadIdx.x;
  if (i < (size_t)TT*BB*NN) rs[i] = 1.0f;   // +I contribution to degree
}

// ---- K1: base = xt@Wd + bd; DE1/2 = tanh(base*E1/2), direct stores ----
__global__ __launch_bounds__(256) void k1_de(const u16* __restrict__ xt,
    const float* __restrict__ Wd, const float* __restrict__ bd,
    const float* __restrict__ E1, const float* __restrict__ E2,
    u16* __restrict__ DE1g, u16* __restrict__ DE2g){
  __shared__ __align__(16) u16 sWd[64*72];   // W^T [o][c]
  const int tid = threadIdx.x, lane = tid & 63, wid = tid >> 6;
  const int l15 = lane & 15, lr4 = lane >> 4;
  const int it = blockIdx.x, b = blockIdx.y, t = blockIdx.z;
  const int n0 = it * 64;
  for (int k = tid; k < 4096; k += 256){
    const int o = k & 63, c = k >> 6;
    sWd[o*72 + c] = f2bu(Wd[(size_t)t*4096 + c*64 + o]);
  }
  __syncthreads();
  const size_t tb = (size_t)t*BB + b;
  const u16* gx = xt + (tb*NN + n0)*CC;
  const int wrow = wid * 16;
  const f32x4 fz = {0.f,0.f,0.f,0.f};
  f32x4 acc[4] = {fz, fz, fz, fz};
  #pragma unroll
  for (int ks = 0; ks < 2; ++ks){
    const int ko = ks*32;
    const s16x8 a = *(const s16x8*)(gx + (wrow + l15)*CC + ko + (lr4 << 3));
    #pragma unroll
    for (int v = 0; v < 4; ++v)
      acc[v] = MFMA16(a, ld72(sWd, v*16, ko, lane), acc[v]);
  }
  #pragma unroll
  for (int v = 0; v < 4; ++v){
    const int o = v*16 + l15;
    const float bdv = bd[t*OO + o];
    #pragma unroll
    for (int e = 0; e < 4; ++e){
      const int n = n0 + wrow + (lr4 << 2) + e;
      const float base = acc[v][e] + bdv;
      const size_t eo = ((size_t)t*NN + n)*OO + o;
      const size_t so = (tb*NN + n)*OO + o;
      DE1g[so] = f2bu(tanh_sgn(base * E1[eo]));
      DE2g[so] = f2bu(tanh_sgn(base * E2[eo]));
    }
  }
}

// ------- K23: fused M build + antisym + tanh/relu + rowsum, A in bf16 -------
// pair tile (ti,tj), 128x128. Zero barriers; direct-global frag loads;
// Q stored direct to global; P transposed via wave-private LDS region.
__global__ __launch_bounds__(256) void k23(const u16* __restrict__ DE1g,
    const u16* __restrict__ DE2g, u16* __restrict__ Abuf,
    float* __restrict__ rowsum, int t0){
  __shared__ __align__(16) u16 qp[4*4608];   // 9KB per wave (64x72)
  const int tid = threadIdx.x, lane = tid & 63, wid = tid >> 6;
  const int l15 = lane & 15, lr4 = lane >> 4;
  int pp = blockIdx.x, ti = 0, tj = 0;
  for (ti = 0; ti < 8; ++ti){ const int cnt = 8 - ti; if (pp < cnt){ tj = ti + pp; break; } pp -= cnt; }
  const bool diag = (ti == tj);
  const int b = blockIdx.y, t = t0 + blockIdx.z;
  const size_t tb = (size_t)t*BB + b;
  const u16* g1i = DE1g + (tb*NN + (size_t)ti*128)*OO;
  const u16* g2i = DE2g + (tb*NN + (size_t)ti*128)*OO;
  const u16* g1j = DE1g + (tb*NN + (size_t)tj*128)*OO;
  const u16* g2j = DE2g + (tb*NN + (size_t)tj*128)*OO;
  const int ro = (wid >> 1) * 64, co = (wid & 1) * 64;
  const f32x4 fz = {0.f,0.f,0.f,0.f};
  f32x4 z1[4][4], z2[4][4];
  #pragma unroll
  for (int u = 0; u < 4; ++u)
    #pragma unroll
    for (int v = 0; v < 4; ++v){ z1[u][v] = fz; z2[u][v] = fz; }
  #pragma unroll
  for (int ks = 0; ks < 2; ++ks){
    const int ko = ks * 32;
    s16x8 b1[4], b2[4];
    #pragma unroll
    for (int v = 0; v < 4; ++v){
      b1[v] = *(const s16x8*)(g2j + (co + v*16 + l15)*OO + ko + (lr4 << 3));
      b2[v] = *(const s16x8*)(g1j + (co + v*16 + l15)*OO + ko + (lr4 << 3));
    }
    #pragma unroll
    for (int u = 0; u < 4; ++u){
      const s16x8 a1 = *(const s16x8*)(g1i + (ro + u*16 + l15)*OO + ko + (lr4 << 3));
      const s16x8 a2 = *(const s16x8*)(g2i + (ro + u*16 + l15)*OO + ko + (lr4 << 3));
      #pragma unroll
      for (int v = 0; v < 4; ++v){
        z1[u][v] = MFMA16(a1, b1[v], z1[u][v]);
        z2[u][v] = MFMA16(a2, b2[v], z2[u][v]);
      }
    }
  }
  // elementwise: q = relu(tanh(d)), p = relu(tanh(-d)); Q direct store
  u16* Ag = Abuf + ((size_t)blockIdx.z*BB + b)*NN*NN;
  float rowp[4][4]; float colp[4] = {0.f,0.f,0.f,0.f};
  #pragma unroll
  for (int u = 0; u < 4; ++u){ rowp[u][0]=rowp[u][1]=rowp[u][2]=rowp[u][3]=0.f; }
  #pragma unroll
  for (int u = 0; u < 4; ++u)
    #pragma unroll
    for (int v = 0; v < 4; ++v)
      #pragma unroll
      for (int e = 0; e < 4; ++e){
        const float d = z1[u][v][e] - z2[u][v][e];
        const float tt = tanh_pos(fabsf(d));
        const float q = d > 0.f ? tt : 0.f;
        const float p = tt - q;
        rowp[u][e] += q; colp[v] += p;
        z2[u][v][e] = p;
        const int rl = ro + u*16 + (lr4 << 2) + e;   // local row in 128-tile
        const int cl = co + v*16 + l15;              // local col
        float qs = q;
        if (diag && rl == cl) qs += 1.0f;            // fold identity into A
        Ag[(size_t)(ti*128 + rl)*NN + tj*128 + cl] = f2bu(qs);
      }
  float* rsg = rowsum + tb*NN;
  #pragma unroll
  for (int u = 0; u < 4; ++u)
    #pragma unroll
    for (int e = 0; e < 4; ++e){
      float r = rowp[u][e];
      r += __shfl_xor(r, 1); r += __shfl_xor(r, 2);
      r += __shfl_xor(r, 4); r += __shfl_xor(r, 8);
      if (l15 == 0)
        atomicAdd(&rsg[ti*128 + ro + u*16 + (lr4 << 2) + e], r);
    }
  if (!diag){
    #pragma unroll
    for (int v = 0; v < 4; ++v){
      float c = colp[v];
      c += __shfl_xor(c, 16); c += __shfl_xor(c, 32);
      if (lane < 16)
        atomicAdd(&rsg[tj*128 + co + v*16 + lane], c);
    }
    // P^T via wave-private LDS (transpose scatter, coalesced copyout)
    u16* w = qp + wid * 4608;
    #pragma unroll
    for (int u = 0; u < 4; ++u)
      #pragma unroll
      for (int v = 0; v < 4; ++v)
        #pragma unroll
        for (int e = 0; e < 4; ++e)
          w[(v*16 + l15)*72 + u*16 + (lr4 << 2) + e] = f2bu(z2[u][v][e]);
    asm volatile("s_waitcnt lgkmcnt(0)" ::: "memory");
    #pragma unroll
    for (int rr = 0; rr < 8; ++rr){
      const int r = rr*8 + (lane >> 3);
      const s16x8 val = *(const s16x8*)(w + r*72 + ((lane & 7) << 3));
      *(s16x8*)(Ag + (size_t)(tj*128 + co + r)*NN + ti*128 + ro + ((lane & 7) << 3)) = val;
    }
  }
}

// ---- K3b: xdw' = 0.475*dis*x@Wd ; xsw' = 0.475*x@Ws  (stored [o][n] bf16)
//      x0w = 0.05*x@W0 + all biases (stored natural [n][o] bf16) ----
__global__ __launch_bounds__(256) void k3b(const u16* __restrict__ xt,
    const float* __restrict__ Wd, const float* __restrict__ Ws,
    const float* __restrict__ W0, const float* __restrict__ bd,
    const float* __restrict__ bs, const float* __restrict__ b0,
    const float* __restrict__ rowsum, u16* __restrict__ xdwT,
    u16* __restrict__ xswT, u16* __restrict__ x0w, int t0){
  __shared__ __align__(16) u16 sW[64*72];
  const int tid = threadIdx.x, lane = tid & 63, wid = tid >> 6;
  const int l15 = lane & 15, lr4 = lane >> 4;
  const int it = blockIdx.x, b = blockIdx.y, t = t0 + blockIdx.z;
  const size_t tb = (size_t)t*BB + b;
  const int n0 = it * 128, wrow = wid * 32;
  const float* rsb = rowsum + tb*NN + n0;
  float dis[2][4];
  #pragma unroll
  for (int u = 0; u < 2; ++u)
    #pragma unroll
    for (int e = 0; e < 4; ++e)
      dis[u][e] = rsqrtf(rsb[wrow + u*16 + (lr4 << 2) + e]);
  float badd[4];
  #pragma unroll
  for (int v = 0; v < 4; ++v){
    const int o = v*16 + l15;
    badd[v] = 0.475f*(bd[t*OO + o] + bs[t*OO + o]) + 0.05f*b0[o];
  }
  const u16* gx = xt + (tb*NN + n0)*CC;
  const f32x4 fz = {0.f,0.f,0.f,0.f};
  for (int pass = 0; pass < 3; ++pass){
    __syncthreads();
    {
      const float* Wsrc = (pass == 0) ? (Wd + (size_t)t*4096)
                        : (pass == 1) ? (Ws + (size_t)t*4096) : W0;
      const float scale = (pass == 2) ? 0.05f : 0.475f;
      for (int k = tid; k < 4096; k += 256){
        const int o = k & 63, c = k >> 6;
        sW[o*72 + c] = f2bu(scale * Wsrc[c*64 + o]);
      }
    }
    __syncthreads();
    f32x4 acc[2][4];
    #pragma unroll
    for (int u = 0; u < 2; ++u)
      #pragma unroll
      for (int v = 0; v < 4; ++v) acc[u][v] = fz;
    #pragma unroll
    for (int ks = 0; ks < 2; ++ks){
      const int ko = ks*32;
      s16x8 bw[4];
      #pragma unroll
      for (int v = 0; v < 4; ++v) bw[v] = ld72(sW, v*16, ko, lane);
      #pragma unroll
      for (int u = 0; u < 2; ++u){
        const s16x8 a = *(const s16x8*)(gx + (wrow + u*16 + l15)*CC + ko + (lr4 << 3));
        #pragma unroll
        for (int v = 0; v < 4; ++v) acc[u][v] = MFMA16(a, bw[v], acc[u][v]);
      }
    }
    #pragma unroll
    for (int u = 0; u < 2; ++u)
      #pragma unroll
      for (int v = 0; v < 4; ++v){
        const int o = v*16 + l15;
        #pragma unroll
        for (int e = 0; e < 4; ++e){
          const int nl = wrow + u*16 + (lr4 << 2) + e;
          float val = acc[u][v][e];
          if (pass == 0){
            xdwT[(tb*OO + o)*NN + n0 + nl] = f2bu(val * dis[u][e]);
          } else if (pass == 1){
            xswT[(tb*OO + o)*NN + n0 + nl] = f2bu(val);
          } else {
            x0w[(tb*NN + n0 + nl)*OO + o] = f2bu(val + badd[v]);
          }
        }
      }
  }
}

// ---- K4: outT = dis_i*((A+I)@xdw') + adj@xsw'  — zero LDS, zero barriers ----
__global__ __launch_bounds__(256) void k4(const u16* __restrict__ Abuf,
    const u16* __restrict__ adjb, const u16* __restrict__ xdwT,
    const u16* __restrict__ xswT, const float* __restrict__ rowsum,
    float* __restrict__ outT, int t0){
  const int tid = threadIdx.x, lane = tid & 63, wid = tid >> 6;
  const int l15 = lane & 15, lr4 = lane >> 4;
  const int it = blockIdx.x, b = blockIdx.y, tl = blockIdx.z, t = t0 + tl;
  const size_t tb = (size_t)t*BB + b;
  const u16* Ag = Abuf + ((size_t)tl*BB + b)*NN*NN;
  const u16* xd = xdwT + tb*OO*NN;
  const u16* xs = xswT + tb*OO*NN;
  const int i0 = it * 128, wrow = wid * 32;
  const f32x4 fz = {0.f,0.f,0.f,0.f};
  f32x4 ad[2][4], as_[2][4];
  #pragma unroll
  for (int u = 0; u < 2; ++u)
    #pragma unroll
    for (int v = 0; v < 4; ++v){ ad[u][v] = fz; as_[u][v] = fz; }
  for (int tj = 0; tj < 16; ++tj){
    const int j0 = tj * 64;
    #pragma unroll
    for (int ks = 0; ks < 2; ++ks){
      const int ko = j0 + ks*32 + (lr4 << 3);
      s16x8 bD[4], bS[4];
      #pragma unroll
      for (int v = 0; v < 4; ++v){
        bD[v] = *(const s16x8*)(xd + (size_t)(v*16 + l15)*NN + ko);
        bS[v] = *(const s16x8*)(xs + (size_t)(v*16 + l15)*NN + ko);
      }
      #pragma unroll
      for (int u = 0; u < 2; ++u){
        const s16x8 aA = *(const s16x8*)(Ag   + (size_t)(i0 + wrow + u*16 + l15)*NN + ko);
        const s16x8 aJ = *(const s16x8*)(adjb + (size_t)(i0 + wrow + u*16 + l15)*NN + ko);
        #pragma unroll
        for (int v = 0; v < 4; ++v){
          ad[u][v]  = MFMA16(aA, bD[v], ad[u][v]);
          as_[u][v] = MFMA16(aJ, bS[v], as_[u][v]);
        }
      }
    }
  }
  const float* rsb = rowsum + tb*NN + i0;
  float dis[2][4];
  #pragma unroll
  for (int u = 0; u < 2; ++u)
    #pragma unroll
    for (int e = 0; e < 4; ++e)
      dis[u][e] = rsqrtf(rsb[wrow + u*16 + (lr4 << 2) + e]);
  #pragma unroll
  for (int u = 0; u < 2; ++u)
    #pragma unroll
    for (int v = 0; v < 4; ++v){
      const int o = v*16 + l15;
      const int nl = i0 + wrow + u*16 + (lr4 << 2);
      #pragma unroll
      for (int e = 0; e < 4; ++e)
        outT[(tb*NN + nl + e)*OO + o] = dis[u][e]*ad[u][v][e] + as_[u][v][e];
    }
}

// ---------------- K5: out = transpose(outT + x0w) -> [B,N,O,T] ----------
__global__ __launch_bounds__(256) void k5(const float* __restrict__ outT,
                                          const u16* __restrict__ x0w,
                                          float* __restrict__ out){
  __shared__ float s[16*64*12];
  const int tid = threadIdx.x;
  const int nb = blockIdx.x, b = blockIdx.y;
  const int n0 = nb * 16;
  for (int t = 0; t < TT; ++t){
    for (int k = tid; k < 1024; k += 256){
      const int r = k >> 6, o = k & 63;
      const size_t idx = (((size_t)t*BB + b)*NN + n0 + r)*OO + o;
      s[(r*64 + o)*12 + t] = outT[idx] + b2f(x0w[idx]);
    }
  }
  __syncthreads();
  float* dst = out + (size_t)(b*NN + n0)*OO*TT;
  for (int k = tid; k < 16*64*12; k += 256) dst[k] = s[k];
}

extern "C" void kernel_launch(void* const* d_in, const int* in_sizes, int n_in,
                              void* d_out, int out_size, void* d_ws, size_t ws_size,
                              hipStream_t stream) {
  const float* x   = (const float*)d_in[0];
  const float* adj = (const float*)d_in[1];
  const float* W0  = (const float*)d_in[2];
  const float* b0  = (const float*)d_in[3];
  const float* Ws  = (const float*)d_in[4];
  const float* bs  = (const float*)d_in[5];
  const float* Wd  = (const float*)d_in[6];
  const float* bd  = (const float*)d_in[7];
  const float* E1  = (const float*)d_in[8];
  const float* E2  = (const float*)d_in[9];
  float* out = (float*)d_out;

  char* w = (char*)d_ws;
  size_t off = 0;
  auto take = [&](size_t bytes) -> char* {
    char* p = w + off;
    off += bytes; off = (off + 255) & ~(size_t)255;
    return p;
  };
  const size_t NE = (size_t)TT*BB*NN*OO;
  u16*   xt    = (u16*)  take(NE*2);
  u16*   adjb  = (u16*)  take((size_t)NN*NN*2);
  u16*   DE1   = (u16*)  take(NE*2);
  u16*   DE2   = (u16*)  take(NE*2);
  float* rowsum= (float*)take((size_t)TT*BB*NN*4);
  u16*   xdwT  = (u16*)  take(NE*2);
  u16*   xswT  = (u16*)  take(NE*2);
  u16*   x0w   = (u16*)  take(NE*2);
  float* outT  = (float*)take(NE*4);
  const size_t perT = (size_t)BB*NN*NN*2;
  size_t rem = (ws_size > off) ? (ws_size - off) : 0;
  int tc = (int)(rem / perT);
  if (tc < 1) tc = 1;
  if (tc > TT) tc = TT;
  u16* Abuf = (u16*)(w + off);

  k0_transpose<<<dim3(NN, BB), 256, 0, stream>>>(x, xt);
  kadj<<<dim3((NN*NN)/1024), 256, 0, stream>>>(adj, adjb);
  k1_de<<<dim3(16, BB, TT), 256, 0, stream>>>(xt, Wd, bd, E1, E2, DE1, DE2);
  kinit<<<dim3((TT*BB*NN + 255)/256), 256, 0, stream>>>(rowsum);

  for (int t0 = 0; t0 < TT; t0 += tc){
    const int nt = (t0 + tc <= TT) ? tc : (TT - t0);
    k23<<<dim3(36, BB, nt), 256, 0, stream>>>(DE1, DE2, Abuf, rowsum, t0);
    k3b<<<dim3(8, BB, nt), 256, 0, stream>>>(xt, Wd, Ws, W0, bd, bs, b0,
                                             rowsum, xdwT, xswT, x0w, t0);
    k4 <<<dim3(8, BB, nt), 256, 0, stream>>>(Abuf, adjb, xdwT, xswT,
                                             rowsum, outT, t0);
  }
  k5<<<dim3(NN/16, BB), 256, 0, stream>>>(outT, x0w, out);
}